// Round 2
// baseline (1532.549 us; speedup 1.0000x reference)
//
#include <hip/hip_runtime.h>
#include <math.h>

#define B_PAIRS 4096
#define NNODES  64
#define NEDGES  256
#define FDIM    128
#define HDIM    64
#define FPDIM   2048
#define MDIM    256

// ---------------------------------------------------------------------------
// Kernel 1: per-graph GCN encoder. One block = one (pair, drug) graph.
// block = 256 threads (4 waves). LDS ~54 KB -> 2 blocks/CU.
// ---------------------------------------------------------------------------
__global__ __launch_bounds__(256, 2)
void encode_kernel(const float* __restrict__ x1, const float* __restrict__ x2,
                   const int* __restrict__ e1, const int* __restrict__ e2,
                   const float* __restrict__ W1, const float* __restrict__ b1,
                   const float* __restrict__ W2, const float* __restrict__ b2,
                   float* __restrict__ hbuf) {
    const int gid  = blockIdx.x;          // 0..8191
    const int drug = gid >> 12;           // 0 or 1
    const int b    = gid & (B_PAIRS - 1);
    const float* x  = (drug ? x2 : x1) + (size_t)b * NNODES * FDIM;
    const int*   eg = (drug ? e2 : e1) + (size_t)b * 2 * NEDGES;

    // xs (64x129, 33KB) is reused as hh (64x65) after matmul1.
    __shared__ float xs[NNODES][FDIM + 1];      // stride 129 -> conflict-free col reads
    __shared__ float xw[NNODES][HDIM + 1];      // stride 65
    __shared__ int   src_e[NEDGES], dst_e[NEDGES];
    __shared__ float w_e[NEDGES];
    __shared__ float norm_s[NNODES];
    __shared__ int   cnt_s[NNODES], off_s[NNODES];
    __shared__ int   elist[NEDGES];
    float (*hh)[HDIM + 1] = (float(*)[HDIM + 1])&xs[0][0];   // alias (xs dead after matmul1)

    const int t = threadIdx.x;

    // ---- load edges, degree, CSR (deterministic rank-based placement) ----
    if (t < NEDGES) {
        src_e[t] = eg[t];
        dst_e[t] = eg[NEDGES + t];
    }
    if (t < NNODES) cnt_s[t] = 0;
    __syncthreads();
    if (t < NEDGES) atomicAdd(&cnt_s[dst_e[t]], 1);
    __syncthreads();
    if (t < NNODES) norm_s[t] = rsqrtf((float)(cnt_s[t] + 1));   // +1 self-loop
    if (t == 0) {
        int acc = 0;
        for (int i = 0; i < NNODES; ++i) { off_s[i] = acc; acc += cnt_s[i]; }
    }
    __syncthreads();
    if (t < NEDGES) {
        const int d = dst_e[t];
        w_e[t] = norm_s[src_e[t]] * norm_s[d];
        int r = 0;
        for (int i = 0; i < NEDGES; ++i)
            r += (i < t && dst_e[i] == d) ? 1 : 0;     // rank among same-dst edges
        elist[off_s[d] + r] = t;
    }

    // ---- stage x into LDS (coalesced float4) ----
    {
        const float4* xg = (const float4*)x;   // 2048 float4, 32 per row
        #pragma unroll
        for (int i = 0; i < 8; ++i) {
            const int f = t + i * 256;
            const int r = f >> 5;
            const int c = (f & 31) << 2;
            float4 v = xg[f];
            xs[r][c + 0] = v.x; xs[r][c + 1] = v.y;
            xs[r][c + 2] = v.z; xs[r][c + 3] = v.w;
        }
    }
    __syncthreads();

    const int rrow  = t >> 2;            // 0..63
    const int cbase = (t & 3) << 4;      // 0,16,32,48

    // ---- matmul1: xw = x @ W1   (64x128 @ 128x64) ----
    {
        float acc[16];
        #pragma unroll
        for (int c = 0; c < 16; ++c) acc[c] = 0.f;
        for (int k = 0; k < FDIM; ++k) {
            const float xv = xs[rrow][k];
            #pragma unroll
            for (int c = 0; c < 16; c += 4) {
                const float4 w = *(const float4*)(W1 + (size_t)k * HDIM + cbase + c);
                acc[c + 0] += xv * w.x; acc[c + 1] += xv * w.y;
                acc[c + 2] += xv * w.z; acc[c + 3] += xv * w.w;
            }
        }
        #pragma unroll
        for (int c = 0; c < 16; ++c) xw[rrow][cbase + c] = acc[c];
    }
    __syncthreads();
    // NOTE: from here xs is dead; hh aliases it.

    // ---- gather1: h1 = relu(aggregate(xw) + b1) ----
    {
        const int n  = rrow;
        const float nn = norm_s[n];
        const float wself = nn * nn;
        float acc[16];
        #pragma unroll
        for (int c = 0; c < 16; ++c) acc[c] = xw[n][cbase + c] * wself;
        const int cn = cnt_s[n], o = off_s[n];
        for (int j = 0; j < cn; ++j) {
            const int e = elist[o + j];
            const int s = src_e[e];
            const float w = w_e[e];
            #pragma unroll
            for (int c = 0; c < 16; ++c) acc[c] += xw[s][cbase + c] * w;
        }
        #pragma unroll
        for (int c = 0; c < 16; ++c) {
            const float v = acc[c] + b1[cbase + c];
            hh[n][cbase + c] = v > 0.f ? v : 0.f;
        }
    }
    __syncthreads();

    // ---- matmul2: xw2 = h1 @ W2   (64x64 @ 64x64), overwrite xw ----
    {
        float acc[16];
        #pragma unroll
        for (int c = 0; c < 16; ++c) acc[c] = 0.f;
        for (int k = 0; k < HDIM; ++k) {
            const float hv = hh[rrow][k];
            #pragma unroll
            for (int c = 0; c < 16; c += 4) {
                const float4 w = *(const float4*)(W2 + (size_t)k * HDIM + cbase + c);
                acc[c + 0] += hv * w.x; acc[c + 1] += hv * w.y;
                acc[c + 2] += hv * w.z; acc[c + 3] += hv * w.w;
            }
        }
        __syncthreads();          // all reads of hh done before xw overwrite below
        #pragma unroll
        for (int c = 0; c < 16; ++c) xw[rrow][cbase + c] = acc[c];
    }
    __syncthreads();

    // ---- gather2: h2 = relu(aggregate(xw2) + b2), overwrite hh ----
    {
        const int n  = rrow;
        const float nn = norm_s[n];
        const float wself = nn * nn;
        float acc[16];
        #pragma unroll
        for (int c = 0; c < 16; ++c) acc[c] = xw[n][cbase + c] * wself;
        const int cn = cnt_s[n], o = off_s[n];
        for (int j = 0; j < cn; ++j) {
            const int e = elist[o + j];
            const int s = src_e[e];
            const float w = w_e[e];
            #pragma unroll
            for (int c = 0; c < 16; ++c) acc[c] += xw[s][cbase + c] * w;
        }
        #pragma unroll
        for (int c = 0; c < 16; ++c) {
            const float v = acc[c] + b2[cbase + c];
            hh[n][cbase + c] = v > 0.f ? v : 0.f;
        }
    }
    __syncthreads();

    // ---- mean pool over nodes ----
    if (t < HDIM) {
        float s = 0.f;
        for (int n = 0; n < NNODES; ++n) s += hh[n][t];
        hbuf[((size_t)drug * B_PAIRS + b) * HDIM + t] = s * (1.0f / NNODES);
    }
}

// ---------------------------------------------------------------------------
// Kernel 2: G[half] = fp_half @ Wm1[fp-rows-half]   (4096x2048 @ 2048x256)
// grid (64, 4, 2); block 256; tile 64x64, BK=32. Disjoint outputs, no atomics.
// ---------------------------------------------------------------------------
__global__ __launch_bounds__(256, 2)
void mlp_gemm_kernel(const float* __restrict__ fp1, const float* __restrict__ fp2,
                     const float* __restrict__ Wm1, float* __restrict__ G) {
    const int bm = blockIdx.x, bn = blockIdx.y, half = blockIdx.z;
    const float* A  = half ? fp2 : fp1;                                  // [4096][2048]
    const float* Bw = Wm1 + (size_t)(2 * HDIM + half * FPDIM) * MDIM;    // [2048][256]
    float* Gh = G + (size_t)half * B_PAIRS * MDIM;

    __shared__ float As[64][33];   // 64x32 tile, stride 33: conflict-free column reads
    __shared__ float Bs[32][68];   // 32x64 tile, stride 68 (=17*16B rows): was [32][36] -> OOB/race BUG

    const int t  = threadIdx.x;
    const int tx = t & 15, ty = t >> 4;
    const int ty4 = ty << 2, tx4 = tx << 2;
    const int row0 = bm * 64, col0 = bn * 64;

    float acc[4][4];
    #pragma unroll
    for (int i = 0; i < 4; ++i)
        #pragma unroll
        for (int j = 0; j < 4; ++j) acc[i][j] = 0.f;

    for (int kt = 0; kt < FPDIM; kt += 32) {
        // stage A tile 64x32 (8 floats / thread)
        {
            const int f = t << 3;
            const int r = f >> 5, c = f & 31;
            const float4* ag = (const float4*)(A + (size_t)(row0 + r) * FPDIM + kt + c);
            const float4 v0 = ag[0], v1 = ag[1];
            As[r][c + 0] = v0.x; As[r][c + 1] = v0.y; As[r][c + 2] = v0.z; As[r][c + 3] = v0.w;
            As[r][c + 4] = v1.x; As[r][c + 5] = v1.y; As[r][c + 6] = v1.z; As[r][c + 7] = v1.w;
        }
        // stage B tile 32x64 (8 floats / thread)
        {
            const int f = t << 3;
            const int r = f >> 6, c = f & 63;
            const float4* bg = (const float4*)(Bw + (size_t)(kt + r) * MDIM + col0 + c);
            *(float4*)&Bs[r][c]     = bg[0];
            *(float4*)&Bs[r][c + 4] = bg[1];
        }
        __syncthreads();
        #pragma unroll
        for (int kk = 0; kk < 32; ++kk) {
            const float a0 = As[ty4 + 0][kk];
            const float a1 = As[ty4 + 1][kk];
            const float a2 = As[ty4 + 2][kk];
            const float a3 = As[ty4 + 3][kk];
            const float4 bv = *(const float4*)&Bs[kk][tx4];
            acc[0][0] += a0 * bv.x; acc[0][1] += a0 * bv.y; acc[0][2] += a0 * bv.z; acc[0][3] += a0 * bv.w;
            acc[1][0] += a1 * bv.x; acc[1][1] += a1 * bv.y; acc[1][2] += a1 * bv.z; acc[1][3] += a1 * bv.w;
            acc[2][0] += a2 * bv.x; acc[2][1] += a2 * bv.y; acc[2][2] += a2 * bv.z; acc[2][3] += a2 * bv.w;
            acc[3][0] += a3 * bv.x; acc[3][1] += a3 * bv.y; acc[3][2] += a3 * bv.z; acc[3][3] += a3 * bv.w;
        }
        __syncthreads();
    }
    #pragma unroll
    for (int i = 0; i < 4; ++i) {
        float4 v = make_float4(acc[i][0], acc[i][1], acc[i][2], acc[i][3]);
        *(float4*)(Gh + (size_t)(row0 + ty4 + i) * MDIM + col0 + tx4) = v;
    }
}

// ---------------------------------------------------------------------------
// Kernel 3: per-pair fuse: hidden = relu(G1+G2 + [h1|h2]@Wm1[0:128] + bm1);
//           out = sigmoid(hidden . Wm2 + bm2)
// ---------------------------------------------------------------------------
__global__ __launch_bounds__(256, 4)
void fuse_kernel(const float* __restrict__ hbuf, const float* __restrict__ G,
                 const float* __restrict__ Wm1, const float* __restrict__ bm1,
                 const float* __restrict__ Wm2, const float* __restrict__ bm2,
                 float* __restrict__ out) {
    const int b = blockIdx.x;
    const int t = threadIdx.x;
    __shared__ float h12[2 * HDIM];
    __shared__ float red[4];

    if (t < HDIM)           h12[t] = hbuf[(size_t)b * HDIM + t];
    else if (t < 2 * HDIM)  h12[t] = hbuf[(size_t)(B_PAIRS + b) * HDIM + (t - HDIM)];
    __syncthreads();

    float acc = G[(size_t)b * MDIM + t]
              + G[(size_t)B_PAIRS * MDIM + (size_t)b * MDIM + t]
              + bm1[t];
    for (int k = 0; k < 2 * HDIM; ++k)
        acc += h12[k] * Wm1[(size_t)k * MDIM + t];

    const float hidden = acc > 0.f ? acc : 0.f;
    float v = hidden * Wm2[t];
    #pragma unroll
    for (int off = 32; off > 0; off >>= 1) v += __shfl_down(v, off);
    if ((t & 63) == 0) red[t >> 6] = v;
    __syncthreads();
    if (t == 0) {
        const float y = red[0] + red[1] + red[2] + red[3] + bm2[0];
        out[b] = 1.0f / (1.0f + expf(-y));
    }
}

extern "C" void kernel_launch(void* const* d_in, const int* in_sizes, int n_in,
                              void* d_out, int out_size, void* d_ws, size_t ws_size,
                              hipStream_t stream) {
    const float* x1  = (const float*)d_in[0];
    const float* x2  = (const float*)d_in[1];
    const int*   e1  = (const int*)d_in[2];
    const int*   e2  = (const int*)d_in[3];
    const float* fp1 = (const float*)d_in[4];
    const float* fp2 = (const float*)d_in[5];
    const float* W1  = (const float*)d_in[6];
    const float* b1  = (const float*)d_in[7];
    const float* W2  = (const float*)d_in[8];
    const float* b2  = (const float*)d_in[9];
    const float* Wm1 = (const float*)d_in[10];
    const float* bm1 = (const float*)d_in[11];
    const float* Wm2 = (const float*)d_in[12];
    const float* bm2 = (const float*)d_in[13];
    float* out  = (float*)d_out;
    float* hbuf = (float*)d_ws;                                // 2*4096*64 floats (2 MB)
    float* G    = hbuf + (size_t)2 * B_PAIRS * HDIM;           // 2*4096*256 floats (8 MB)

    hipLaunchKernelGGL(encode_kernel, dim3(2 * B_PAIRS), dim3(256), 0, stream,
                       x1, x2, e1, e2, W1, b1, W2, b2, hbuf);
    hipLaunchKernelGGL(mlp_gemm_kernel, dim3(64, 4, 2), dim3(256), 0, stream,
                       fp1, fp2, Wm1, G);
    hipLaunchKernelGGL(fuse_kernel, dim3(B_PAIRS), dim3(256), 0, stream,
                       hbuf, G, Wm1, bm1, Wm2, bm2, out);
}

// Round 3
// 297.505 us; speedup vs baseline: 5.1513x; 5.1513x over previous
//
#include <hip/hip_runtime.h>
#include <math.h>

#define B_PAIRS 4096
#define NNODES  64
#define NEDGES  256
#define FDIM    128
#define HDIM    64
#define FPDIM   2048
#define MDIM    256

typedef __attribute__((ext_vector_type(4))) float f32x4;
typedef __bf16 bf16x8 __attribute__((ext_vector_type(8)));

__device__ __forceinline__ unsigned short f2bf(float f) {
    union { float f; unsigned u; } v; v.f = f;
    unsigned r = v.u + 0x7FFF + ((v.u >> 16) & 1);   // RTNE
    return (unsigned short)(r >> 16);
}
__device__ __forceinline__ unsigned pack2(float a, float b) {
    return (unsigned)f2bf(a) | ((unsigned)f2bf(b) << 16);
}

// ---------------------------------------------------------------------------
// Kernel 0: transpose weights to bf16 once. W1t[n][k]=W1[k][n], W2t[n][k]=W2[k][n]
// ---------------------------------------------------------------------------
__global__ void prep_weights(const float* __restrict__ W1, const float* __restrict__ W2,
                             unsigned short* __restrict__ W1t, unsigned short* __restrict__ W2t) {
    const int t = threadIdx.x;
    for (int i = t; i < HDIM * FDIM; i += 256) {
        const int n = i >> 7, k = i & 127;
        W1t[i] = f2bf(W1[k * HDIM + n]);
    }
    for (int i = t; i < HDIM * HDIM; i += 256) {
        const int n = i >> 6, k = i & 63;
        W2t[i] = f2bf(W2[k * HDIM + n]);
    }
}

// ---------------------------------------------------------------------------
// Kernel 1: per-graph GCN encoder, all-MFMA.
// One block = one (pair,drug) graph. 256 thr = 4 waves; wave mt owns M-rows
// [16mt,16mt+16). LDS layout (bytes), XOR-swizzle byte^=((row&7)<<4) per row:
//   [    0,16384) Xb bf16[64][128]      -> after step1: T2b[0,8K) + T3t[8K,16K)
//   [16384,24576) Ab bf16[64][64]  (A-hat, alive whole kernel)
//   [24576,32768) T1t bf16[64][64]     (overlaps cnt; cnt dead before write)
//   [24576,40960) cnt int[64][64]  (early only)
//   [40960,44544) edges/deg/norm/pool
// ---------------------------------------------------------------------------
__global__ __launch_bounds__(256)
void encode_kernel(const float* __restrict__ x1, const float* __restrict__ x2,
                   const int* __restrict__ e1, const int* __restrict__ e2,
                   const unsigned short* __restrict__ W1t, const float* __restrict__ b1,
                   const unsigned short* __restrict__ W2t, const float* __restrict__ b2,
                   float* __restrict__ hbuf) {
    __shared__ __align__(16) unsigned char lds[44544];
    const int gid  = blockIdx.x;
    const int drug = gid >> 12;
    const int b    = gid & (B_PAIRS - 1);
    const float* x  = (drug ? x2 : x1) + (size_t)b * NNODES * FDIM;
    const int*   eg = (drug ? e2 : e1) + (size_t)b * 2 * NEDGES;

    const int t    = threadIdx.x;
    const int lane = t & 63, wid = t >> 6;
    const int lr   = lane & 15, lg = lane >> 4;
    const int mt   = wid;
    const int m0   = 16 * mt + 4 * lg;      // D-rows this lane owns (all steps)

    int*   cnt  = (int*)(lds + 24576);
    int*   srcs = (int*)(lds + 40960);
    int*   dsts = (int*)(lds + 41984);
    int*   deg  = (int*)(lds + 43008);
    float* nrm  = (float*)(lds + 43264);
    float* pool = (float*)(lds + 43520);

    // fire x loads early (32 floats/thread), overlap with edge/A-hat phase
    float4 xv[8];
    const float4* xg = (const float4*)x;
    #pragma unroll
    for (int i = 0; i < 8; ++i) xv[i] = xg[t + 256 * i];

    #pragma unroll
    for (int i = 0; i < 4; ++i) ((int4*)cnt)[t + 256 * i] = make_int4(0, 0, 0, 0);
    if (t < NEDGES) { srcs[t] = eg[t]; dsts[t] = eg[NEDGES + t]; }
    if (t < NNODES) deg[t] = 0;
    __syncthreads();                                           // B0
    if (t < NEDGES) {
        atomicAdd(&deg[dsts[t]], 1);
        atomicAdd(&cnt[dsts[t] * 64 + srcs[t]], 1);            // multiplicity (deterministic)
    }
    __syncthreads();                                           // B1
    if (t < NNODES) nrm[t] = rsqrtf((float)deg[t] + 1.0f);     // +1 self-loop
    __syncthreads();                                           // B2

    // build A-hat bf16 swizzled: Ab[d][s] = (cnt + (d==s)) * nrm[d]*nrm[s]
    {
        const int r = t >> 2, c0 = (t & 3) << 4;
        const float nr = nrm[r];
        unsigned char* arow = lds + 16384 + r * 128;
        const unsigned sw = (r & 7) << 4;
        #pragma unroll
        for (int j = 0; j < 16; j += 2) {
            const int c = c0 + j;
            const float v0 = (float)(cnt[r * 64 + c]     + (r == c     ? 1 : 0)) * nr * nrm[c];
            const float v1 = (float)(cnt[r * 64 + c + 1] + (r == c + 1 ? 1 : 0)) * nr * nrm[c + 1];
            *(unsigned*)(arow + (((unsigned)(2 * c)) ^ sw)) = pack2(v0, v1);
        }
    }
    // stage Xb bf16 swizzled (node-major [64][128])
    #pragma unroll
    for (int i = 0; i < 8; ++i) {
        const int f = t + 256 * i, r = f >> 5, c = (f & 31) << 2;
        const unsigned lo = pack2(xv[i].x, xv[i].y);
        const unsigned hi = pack2(xv[i].z, xv[i].w);
        const unsigned off = (unsigned)r * 256 + (((unsigned)(2 * c)) ^ ((unsigned)(r & 7) << 4));
        *(unsigned long long*)(lds + off) = (unsigned long long)lo | ((unsigned long long)hi << 32);
    }
    __syncthreads();                                           // B3

    // ---- step1: T1 = Xb @ W1  (M=node, N=featH, K=128) -> T1t[featH][node]
    {
        f32x4 acc[4];
        #pragma unroll
        for (int nt = 0; nt < 4; ++nt) acc[nt] = (f32x4){0.f, 0.f, 0.f, 0.f};
        const int ar = 16 * mt + lr;
        const unsigned asw = (unsigned)(ar & 7) << 4;
        #pragma unroll
        for (int ks = 0; ks < 4; ++ks) {
            const unsigned kb = 64 * ks + 16 * lg;
            const bf16x8 a = *(const bf16x8*)(lds + (unsigned)ar * 256 + (kb ^ asw));
            #pragma unroll
            for (int nt = 0; nt < 4; ++nt) {
                const bf16x8 bw = *(const bf16x8*)(W1t + (16 * nt + lr) * 128 + 32 * ks + 8 * lg);
                acc[nt] = __builtin_amdgcn_mfma_f32_16x16x32_bf16(a, bw, acc[nt], 0, 0, 0);
            }
        }
        #pragma unroll
        for (int nt = 0; nt < 4; ++nt) {
            const int f = 16 * nt + lr;
            const unsigned lo = pack2(acc[nt][0], acc[nt][1]);
            const unsigned hi = pack2(acc[nt][2], acc[nt][3]);
            const unsigned off = 24576u + (unsigned)f * 128 + (((unsigned)(2 * m0)) ^ ((unsigned)(f & 7) << 4));
            *(unsigned long long*)(lds + off) = (unsigned long long)lo | ((unsigned long long)hi << 32);
        }
    }
    __syncthreads();                                           // B4 (Xb dead now)

    // ---- step2: T2^T = T1t @ A^T (+b1, relu) -> T2b[node][featH] at 0
    {
        f32x4 acc[4];
        #pragma unroll
        for (int nt = 0; nt < 4; ++nt) acc[nt] = (f32x4){0.f, 0.f, 0.f, 0.f};
        const int ar = 16 * mt + lr;                 // featH row of T1t
        const unsigned asw = (unsigned)(ar & 7) << 4;
        #pragma unroll
        for (int ks = 0; ks < 2; ++ks) {
            const unsigned kb = 64 * ks + 16 * lg;
            const bf16x8 a = *(const bf16x8*)(lds + 24576u + (unsigned)ar * 128 + (kb ^ asw));
            #pragma unroll
            for (int nt = 0; nt < 4; ++nt) {
                const int d = 16 * nt + lr;          // B[k=s][col=d] = Ab[d][s..]
                const bf16x8 bw = *(const bf16x8*)(lds + 16384u + (unsigned)d * 128 + (kb ^ ((unsigned)(d & 7) << 4)));
                acc[nt] = __builtin_amdgcn_mfma_f32_16x16x32_bf16(a, bw, acc[nt], 0, 0, 0);
            }
        }
        const float4 b1v = *(const float4*)(b1 + m0);          // bias along featH = m
        #pragma unroll
        for (int nt = 0; nt < 4; ++nt) {
            const int d = 16 * nt + lr;
            const float v0 = fmaxf(acc[nt][0] + b1v.x, 0.f);
            const float v1 = fmaxf(acc[nt][1] + b1v.y, 0.f);
            const float v2 = fmaxf(acc[nt][2] + b1v.z, 0.f);
            const float v3 = fmaxf(acc[nt][3] + b1v.w, 0.f);
            const unsigned off = (unsigned)d * 128 + (((unsigned)(2 * m0)) ^ ((unsigned)(d & 7) << 4));
            *(unsigned long long*)(lds + off) =
                (unsigned long long)pack2(v0, v1) | ((unsigned long long)pack2(v2, v3) << 32);
        }
    }
    __syncthreads();                                           // B5

    // ---- step3: T3 = T2b @ W2 (M=node, N=outH, K=64) -> T3t[outH][node] at 8192
    {
        f32x4 acc[4];
        #pragma unroll
        for (int nt = 0; nt < 4; ++nt) acc[nt] = (f32x4){0.f, 0.f, 0.f, 0.f};
        const int ar = 16 * mt + lr;                 // node row of T2b
        const unsigned asw = (unsigned)(ar & 7) << 4;
        #pragma unroll
        for (int ks = 0; ks < 2; ++ks) {
            const unsigned kb = 64 * ks + 16 * lg;
            const bf16x8 a = *(const bf16x8*)(lds + (unsigned)ar * 128 + (kb ^ asw));
            #pragma unroll
            for (int nt = 0; nt < 4; ++nt) {
                const bf16x8 bw = *(const bf16x8*)(W2t + (16 * nt + lr) * 64 + 32 * ks + 8 * lg);
                acc[nt] = __builtin_amdgcn_mfma_f32_16x16x32_bf16(a, bw, acc[nt], 0, 0, 0);
            }
        }
        #pragma unroll
        for (int nt = 0; nt < 4; ++nt) {
            const int n = 16 * nt + lr;              // outH
            const unsigned lo = pack2(acc[nt][0], acc[nt][1]);
            const unsigned hi = pack2(acc[nt][2], acc[nt][3]);
            const unsigned off = 8192u + (unsigned)n * 128 + (((unsigned)(2 * m0)) ^ ((unsigned)(n & 7) << 4));
            *(unsigned long long*)(lds + off) = (unsigned long long)lo | ((unsigned long long)hi << 32);
        }
    }
    __syncthreads();                                           // B6

    // ---- step4: h2 = Ab @ T3 (+b2, relu) -> pool over nodes
    {
        f32x4 acc[4];
        #pragma unroll
        for (int nt = 0; nt < 4; ++nt) acc[nt] = (f32x4){0.f, 0.f, 0.f, 0.f};
        const int ar = 16 * mt + lr;                 // dst-node row of Ab
        const unsigned asw = (unsigned)(ar & 7) << 4;
        #pragma unroll
        for (int ks = 0; ks < 2; ++ks) {
            const unsigned kb = 64 * ks + 16 * lg;
            const bf16x8 a = *(const bf16x8*)(lds + 16384u + (unsigned)ar * 128 + (kb ^ asw));
            #pragma unroll
            for (int nt = 0; nt < 4; ++nt) {
                const int n = 16 * nt + lr;          // B[k=s][col=outH] = T3t[outH][s..]
                const bf16x8 bw = *(const bf16x8*)(lds + 8192u + (unsigned)n * 128 + (kb ^ ((unsigned)(n & 7) << 4)));
                acc[nt] = __builtin_amdgcn_mfma_f32_16x16x32_bf16(a, bw, acc[nt], 0, 0, 0);
            }
        }
        float p[4];
        #pragma unroll
        for (int nt = 0; nt < 4; ++nt) {
            const float bb = b2[16 * nt + lr];
            float s = 0.f;
            #pragma unroll
            for (int r = 0; r < 4; ++r) s += fmaxf(acc[nt][r] + bb, 0.f);
            p[nt] = s;
        }
        #pragma unroll
        for (int nt = 0; nt < 4; ++nt) {
            p[nt] += __shfl_xor(p[nt], 16, 64);
            p[nt] += __shfl_xor(p[nt], 32, 64);
        }
        if (lg == 0) {
            #pragma unroll
            for (int nt = 0; nt < 4; ++nt) pool[wid * 64 + 16 * nt + lr] = p[nt];
        }
    }
    __syncthreads();                                           // B7
    if (t < HDIM) {
        const float s = pool[t] + pool[64 + t] + pool[128 + t] + pool[192 + t];
        hbuf[((size_t)drug * B_PAIRS + b) * HDIM + t] = s * (1.0f / 64.0f);
    }
}

// ---------------------------------------------------------------------------
// Kernel 2: G[half] = fp_half @ Wm1[fp-rows-half]   (4096x2048 @ 2048x256)
// ---------------------------------------------------------------------------
__global__ __launch_bounds__(256, 2)
void mlp_gemm_kernel(const float* __restrict__ fp1, const float* __restrict__ fp2,
                     const float* __restrict__ Wm1, float* __restrict__ G) {
    const int bm = blockIdx.x, bn = blockIdx.y, half = blockIdx.z;
    const float* A  = half ? fp2 : fp1;
    const float* Bw = Wm1 + (size_t)(2 * HDIM + half * FPDIM) * MDIM;
    float* Gh = G + (size_t)half * B_PAIRS * MDIM;

    __shared__ float As[64][33];
    __shared__ float Bs[32][68];

    const int t  = threadIdx.x;
    const int tx = t & 15, ty = t >> 4;
    const int ty4 = ty << 2, tx4 = tx << 2;
    const int row0 = bm * 64, col0 = bn * 64;

    float acc[4][4];
    #pragma unroll
    for (int i = 0; i < 4; ++i)
        #pragma unroll
        for (int j = 0; j < 4; ++j) acc[i][j] = 0.f;

    for (int kt = 0; kt < FPDIM; kt += 32) {
        {
            const int f = t << 3;
            const int r = f >> 5, c = f & 31;
            const float4* ag = (const float4*)(A + (size_t)(row0 + r) * FPDIM + kt + c);
            const float4 v0 = ag[0], v1 = ag[1];
            As[r][c + 0] = v0.x; As[r][c + 1] = v0.y; As[r][c + 2] = v0.z; As[r][c + 3] = v0.w;
            As[r][c + 4] = v1.x; As[r][c + 5] = v1.y; As[r][c + 6] = v1.z; As[r][c + 7] = v1.w;
        }
        {
            const int f = t << 3;
            const int r = f >> 6, c = f & 63;
            const float4* bg = (const float4*)(Bw + (size_t)(kt + r) * MDIM + col0 + c);
            *(float4*)&Bs[r][c]     = bg[0];
            *(float4*)&Bs[r][c + 4] = bg[1];
        }
        __syncthreads();
        #pragma unroll
        for (int kk = 0; kk < 32; ++kk) {
            const float a0 = As[ty4 + 0][kk];
            const float a1 = As[ty4 + 1][kk];
            const float a2 = As[ty4 + 2][kk];
            const float a3 = As[ty4 + 3][kk];
            const float4 bv = *(const float4*)&Bs[kk][tx4];
            acc[0][0] += a0 * bv.x; acc[0][1] += a0 * bv.y; acc[0][2] += a0 * bv.z; acc[0][3] += a0 * bv.w;
            acc[1][0] += a1 * bv.x; acc[1][1] += a1 * bv.y; acc[1][2] += a1 * bv.z; acc[1][3] += a1 * bv.w;
            acc[2][0] += a2 * bv.x; acc[2][1] += a2 * bv.y; acc[2][2] += a2 * bv.z; acc[2][3] += a2 * bv.w;
            acc[3][0] += a3 * bv.x; acc[3][1] += a3 * bv.y; acc[3][2] += a3 * bv.z; acc[3][3] += a3 * bv.w;
        }
        __syncthreads();
    }
    #pragma unroll
    for (int i = 0; i < 4; ++i) {
        float4 v = make_float4(acc[i][0], acc[i][1], acc[i][2], acc[i][3]);
        *(float4*)(Gh + (size_t)(row0 + ty4 + i) * MDIM + col0 + tx4) = v;
    }
}

// ---------------------------------------------------------------------------
// Kernel 3: fuse + final MLP
// ---------------------------------------------------------------------------
__global__ __launch_bounds__(256, 4)
void fuse_kernel(const float* __restrict__ hbuf, const float* __restrict__ G,
                 const float* __restrict__ Wm1, const float* __restrict__ bm1,
                 const float* __restrict__ Wm2, const float* __restrict__ bm2,
                 float* __restrict__ out) {
    const int b = blockIdx.x;
    const int t = threadIdx.x;
    __shared__ float h12[2 * HDIM];
    __shared__ float red[4];

    if (t < HDIM)           h12[t] = hbuf[(size_t)b * HDIM + t];
    else if (t < 2 * HDIM)  h12[t] = hbuf[(size_t)(B_PAIRS + b) * HDIM + (t - HDIM)];
    __syncthreads();

    float acc = G[(size_t)b * MDIM + t]
              + G[(size_t)B_PAIRS * MDIM + (size_t)b * MDIM + t]
              + bm1[t];
    for (int k = 0; k < 2 * HDIM; ++k)
        acc += h12[k] * Wm1[(size_t)k * MDIM + t];

    const float hidden = acc > 0.f ? acc : 0.f;
    float v = hidden * Wm2[t];
    #pragma unroll
    for (int off = 32; off > 0; off >>= 1) v += __shfl_down(v, off);
    if ((t & 63) == 0) red[t >> 6] = v;
    __syncthreads();
    if (t == 0) {
        const float y = red[0] + red[1] + red[2] + red[3] + bm2[0];
        out[b] = 1.0f / (1.0f + expf(-y));
    }
}

extern "C" void kernel_launch(void* const* d_in, const int* in_sizes, int n_in,
                              void* d_out, int out_size, void* d_ws, size_t ws_size,
                              hipStream_t stream) {
    const float* x1  = (const float*)d_in[0];
    const float* x2  = (const float*)d_in[1];
    const int*   e1  = (const int*)d_in[2];
    const int*   e2  = (const int*)d_in[3];
    const float* fp1 = (const float*)d_in[4];
    const float* fp2 = (const float*)d_in[5];
    const float* W1  = (const float*)d_in[6];
    const float* b1  = (const float*)d_in[7];
    const float* W2  = (const float*)d_in[8];
    const float* b2  = (const float*)d_in[9];
    const float* Wm1 = (const float*)d_in[10];
    const float* bm1 = (const float*)d_in[11];
    const float* Wm2 = (const float*)d_in[12];
    const float* bm2 = (const float*)d_in[13];
    float* out  = (float*)d_out;

    float* hbuf = (float*)d_ws;                                   // 2 MB
    float* G    = hbuf + (size_t)2 * B_PAIRS * HDIM;              // 8 MB
    unsigned short* W1t = (unsigned short*)((char*)d_ws + (size_t)10 * 1024 * 1024);
    unsigned short* W2t = W1t + HDIM * FDIM;

    hipLaunchKernelGGL(prep_weights, dim3(1), dim3(256), 0, stream, W1, W2, W1t, W2t);
    hipLaunchKernelGGL(encode_kernel, dim3(2 * B_PAIRS), dim3(256), 0, stream,
                       x1, x2, e1, e2, W1t, b1, W2t, b2, hbuf);
    hipLaunchKernelGGL(mlp_gemm_kernel, dim3(64, 4, 2), dim3(256), 0, stream,
                       fp1, fp2, Wm1, G);
    hipLaunchKernelGGL(fuse_kernel, dim3(B_PAIRS), dim3(256), 0, stream,
                       hbuf, G, Wm1, bm1, Wm2, bm2, out);
}

// Round 4
// 269.677 us; speedup vs baseline: 5.6829x; 1.1032x over previous
//
#include <hip/hip_runtime.h>
#include <math.h>

#define B_PAIRS 4096
#define NNODES  64
#define NEDGES  256
#define FDIM    128
#define HDIM    64
#define FPDIM   2048
#define MDIM    256
#define KTOT    4224   // 2*HDIM + 2*FPDIM

typedef __attribute__((ext_vector_type(4))) float f32x4;
typedef __bf16 bf16x8 __attribute__((ext_vector_type(8)));

__device__ __forceinline__ unsigned short f2bf(float f) {
    union { float f; unsigned u; } v; v.f = f;
    unsigned r = v.u + 0x7FFF + ((v.u >> 16) & 1);   // RTNE
    return (unsigned short)(r >> 16);
}
__device__ __forceinline__ unsigned pack2(float a, float b) {
    return (unsigned)f2bf(a) | ((unsigned)f2bf(b) << 16);
}

// ---------------------------------------------------------------------------
// Kernel 0a: W1t[n][k]=W1[k][n], W2t[n][k]=W2[k][n] (bf16), grid-strided.
// ---------------------------------------------------------------------------
__global__ void prep_weights(const float* __restrict__ W1, const float* __restrict__ W2,
                             unsigned short* __restrict__ W1t, unsigned short* __restrict__ W2t) {
    const int t0 = blockIdx.x * 256 + threadIdx.x;
    const int stride = gridDim.x * 256;
    for (int i = t0; i < HDIM * FDIM; i += stride) {
        const int n = i >> 7, k = i & 127;
        W1t[i] = f2bf(W1[k * HDIM + n]);
    }
    for (int i = t0; i < HDIM * HDIM; i += stride) {
        const int n = i >> 6, k = i & 63;
        W2t[i] = f2bf(W2[k * HDIM + n]);
    }
}

// ---------------------------------------------------------------------------
// Kernel 0b: Wm1t[n][k] = bf16(Wm1[k][n]), n<256, k<4224. Tiled 32x32 via LDS.
// grid (132, 8), block 256.
// ---------------------------------------------------------------------------
__global__ __launch_bounds__(256)
void prep_wm1(const float* __restrict__ Wm1, unsigned short* __restrict__ Wm1t) {
    __shared__ float tile[32][33];
    const int k0 = blockIdx.x * 32, n0 = blockIdx.y * 32;
    const int t = threadIdx.x;
    const int c = t & 31, r8 = t >> 5;     // c: col, r8: 0..7
    #pragma unroll
    for (int rr = r8; rr < 32; rr += 8)
        tile[rr][c] = Wm1[(size_t)(k0 + rr) * MDIM + n0 + c];
    __syncthreads();
    #pragma unroll
    for (int j = 0; j < 4; ++j) {
        const int n = n0 + r8 + 8 * j;
        Wm1t[(size_t)n * KTOT + k0 + c] = f2bf(tile[c][r8 + 8 * j]);
    }
}

// ---------------------------------------------------------------------------
// Kernel 1: per-graph GCN encoder, all-MFMA (unchanged from R3 — verified).
// ---------------------------------------------------------------------------
__global__ __launch_bounds__(256)
void encode_kernel(const float* __restrict__ x1, const float* __restrict__ x2,
                   const int* __restrict__ e1, const int* __restrict__ e2,
                   const unsigned short* __restrict__ W1t, const float* __restrict__ b1,
                   const unsigned short* __restrict__ W2t, const float* __restrict__ b2,
                   float* __restrict__ hbuf) {
    __shared__ __align__(16) unsigned char lds[44544];
    const int gid  = blockIdx.x;
    const int drug = gid >> 12;
    const int b    = gid & (B_PAIRS - 1);
    const float* x  = (drug ? x2 : x1) + (size_t)b * NNODES * FDIM;
    const int*   eg = (drug ? e2 : e1) + (size_t)b * 2 * NEDGES;

    const int t    = threadIdx.x;
    const int lane = t & 63, wid = t >> 6;
    const int lr   = lane & 15, lg = lane >> 4;
    const int mt   = wid;
    const int m0   = 16 * mt + 4 * lg;

    int*   cnt  = (int*)(lds + 24576);
    int*   srcs = (int*)(lds + 40960);
    int*   dsts = (int*)(lds + 41984);
    int*   deg  = (int*)(lds + 43008);
    float* nrm  = (float*)(lds + 43264);
    float* pool = (float*)(lds + 43520);

    float4 xv[8];
    const float4* xg = (const float4*)x;
    #pragma unroll
    for (int i = 0; i < 8; ++i) xv[i] = xg[t + 256 * i];

    #pragma unroll
    for (int i = 0; i < 4; ++i) ((int4*)cnt)[t + 256 * i] = make_int4(0, 0, 0, 0);
    if (t < NEDGES) { srcs[t] = eg[t]; dsts[t] = eg[NEDGES + t]; }
    if (t < NNODES) deg[t] = 0;
    __syncthreads();                                           // B0
    if (t < NEDGES) {
        atomicAdd(&deg[dsts[t]], 1);
        atomicAdd(&cnt[dsts[t] * 64 + srcs[t]], 1);
    }
    __syncthreads();                                           // B1
    if (t < NNODES) nrm[t] = rsqrtf((float)deg[t] + 1.0f);
    __syncthreads();                                           // B2

    {
        const int r = t >> 2, c0 = (t & 3) << 4;
        const float nr = nrm[r];
        unsigned char* arow = lds + 16384 + r * 128;
        const unsigned sw = (r & 7) << 4;
        #pragma unroll
        for (int j = 0; j < 16; j += 2) {
            const int c = c0 + j;
            const float v0 = (float)(cnt[r * 64 + c]     + (r == c     ? 1 : 0)) * nr * nrm[c];
            const float v1 = (float)(cnt[r * 64 + c + 1] + (r == c + 1 ? 1 : 0)) * nr * nrm[c + 1];
            *(unsigned*)(arow + (((unsigned)(2 * c)) ^ sw)) = pack2(v0, v1);
        }
    }
    #pragma unroll
    for (int i = 0; i < 8; ++i) {
        const int f = t + 256 * i, r = f >> 5, c = (f & 31) << 2;
        const unsigned lo = pack2(xv[i].x, xv[i].y);
        const unsigned hi = pack2(xv[i].z, xv[i].w);
        const unsigned off = (unsigned)r * 256 + (((unsigned)(2 * c)) ^ ((unsigned)(r & 7) << 4));
        *(unsigned long long*)(lds + off) = (unsigned long long)lo | ((unsigned long long)hi << 32);
    }
    __syncthreads();                                           // B3

    // step1: T1 = Xb @ W1 -> T1t[featH][node]
    {
        f32x4 acc[4];
        #pragma unroll
        for (int nt = 0; nt < 4; ++nt) acc[nt] = (f32x4){0.f, 0.f, 0.f, 0.f};
        const int ar = 16 * mt + lr;
        const unsigned asw = (unsigned)(ar & 7) << 4;
        #pragma unroll
        for (int ks = 0; ks < 4; ++ks) {
            const unsigned kb = 64 * ks + 16 * lg;
            const bf16x8 a = *(const bf16x8*)(lds + (unsigned)ar * 256 + (kb ^ asw));
            #pragma unroll
            for (int nt = 0; nt < 4; ++nt) {
                const bf16x8 bw = *(const bf16x8*)(W1t + (16 * nt + lr) * 128 + 32 * ks + 8 * lg);
                acc[nt] = __builtin_amdgcn_mfma_f32_16x16x32_bf16(a, bw, acc[nt], 0, 0, 0);
            }
        }
        #pragma unroll
        for (int nt = 0; nt < 4; ++nt) {
            const int f = 16 * nt + lr;
            const unsigned lo = pack2(acc[nt][0], acc[nt][1]);
            const unsigned hi = pack2(acc[nt][2], acc[nt][3]);
            const unsigned off = 24576u + (unsigned)f * 128 + (((unsigned)(2 * m0)) ^ ((unsigned)(f & 7) << 4));
            *(unsigned long long*)(lds + off) = (unsigned long long)lo | ((unsigned long long)hi << 32);
        }
    }
    __syncthreads();                                           // B4

    // step2: T2^T = T1t @ A^T (+b1, relu) -> T2b[node][featH]
    {
        f32x4 acc[4];
        #pragma unroll
        for (int nt = 0; nt < 4; ++nt) acc[nt] = (f32x4){0.f, 0.f, 0.f, 0.f};
        const int ar = 16 * mt + lr;
        const unsigned asw = (unsigned)(ar & 7) << 4;
        #pragma unroll
        for (int ks = 0; ks < 2; ++ks) {
            const unsigned kb = 64 * ks + 16 * lg;
            const bf16x8 a = *(const bf16x8*)(lds + 24576u + (unsigned)ar * 128 + (kb ^ asw));
            #pragma unroll
            for (int nt = 0; nt < 4; ++nt) {
                const int d = 16 * nt + lr;
                const bf16x8 bw = *(const bf16x8*)(lds + 16384u + (unsigned)d * 128 + (kb ^ ((unsigned)(d & 7) << 4)));
                acc[nt] = __builtin_amdgcn_mfma_f32_16x16x32_bf16(a, bw, acc[nt], 0, 0, 0);
            }
        }
        const float4 b1v = *(const float4*)(b1 + m0);
        #pragma unroll
        for (int nt = 0; nt < 4; ++nt) {
            const int d = 16 * nt + lr;
            const float v0 = fmaxf(acc[nt][0] + b1v.x, 0.f);
            const float v1 = fmaxf(acc[nt][1] + b1v.y, 0.f);
            const float v2 = fmaxf(acc[nt][2] + b1v.z, 0.f);
            const float v3 = fmaxf(acc[nt][3] + b1v.w, 0.f);
            const unsigned off = (unsigned)d * 128 + (((unsigned)(2 * m0)) ^ ((unsigned)(d & 7) << 4));
            *(unsigned long long*)(lds + off) =
                (unsigned long long)pack2(v0, v1) | ((unsigned long long)pack2(v2, v3) << 32);
        }
    }
    __syncthreads();                                           // B5

    // step3: T3 = T2b @ W2 -> T3t[outH][node]
    {
        f32x4 acc[4];
        #pragma unroll
        for (int nt = 0; nt < 4; ++nt) acc[nt] = (f32x4){0.f, 0.f, 0.f, 0.f};
        const int ar = 16 * mt + lr;
        const unsigned asw = (unsigned)(ar & 7) << 4;
        #pragma unroll
        for (int ks = 0; ks < 2; ++ks) {
            const unsigned kb = 64 * ks + 16 * lg;
            const bf16x8 a = *(const bf16x8*)(lds + (unsigned)ar * 128 + (kb ^ asw));
            #pragma unroll
            for (int nt = 0; nt < 4; ++nt) {
                const bf16x8 bw = *(const bf16x8*)(W2t + (16 * nt + lr) * 64 + 32 * ks + 8 * lg);
                acc[nt] = __builtin_amdgcn_mfma_f32_16x16x32_bf16(a, bw, acc[nt], 0, 0, 0);
            }
        }
        #pragma unroll
        for (int nt = 0; nt < 4; ++nt) {
            const int n = 16 * nt + lr;
            const unsigned lo = pack2(acc[nt][0], acc[nt][1]);
            const unsigned hi = pack2(acc[nt][2], acc[nt][3]);
            const unsigned off = 8192u + (unsigned)n * 128 + (((unsigned)(2 * m0)) ^ ((unsigned)(n & 7) << 4));
            *(unsigned long long*)(lds + off) = (unsigned long long)lo | ((unsigned long long)hi << 32);
        }
    }
    __syncthreads();                                           // B6

    // step4: h2 = Ab @ T3 (+b2, relu) -> pool
    {
        f32x4 acc[4];
        #pragma unroll
        for (int nt = 0; nt < 4; ++nt) acc[nt] = (f32x4){0.f, 0.f, 0.f, 0.f};
        const int ar = 16 * mt + lr;
        const unsigned asw = (unsigned)(ar & 7) << 4;
        #pragma unroll
        for (int ks = 0; ks < 2; ++ks) {
            const unsigned kb = 64 * ks + 16 * lg;
            const bf16x8 a = *(const bf16x8*)(lds + 16384u + (unsigned)ar * 128 + (kb ^ asw));
            #pragma unroll
            for (int nt = 0; nt < 4; ++nt) {
                const int n = 16 * nt + lr;
                const bf16x8 bw = *(const bf16x8*)(lds + 8192u + (unsigned)n * 128 + (kb ^ ((unsigned)(n & 7) << 4)));
                acc[nt] = __builtin_amdgcn_mfma_f32_16x16x32_bf16(a, bw, acc[nt], 0, 0, 0);
            }
        }
        float p[4];
        #pragma unroll
        for (int nt = 0; nt < 4; ++nt) {
            const float bb = b2[16 * nt + lr];
            float s = 0.f;
            #pragma unroll
            for (int r = 0; r < 4; ++r) s += fmaxf(acc[nt][r] + bb, 0.f);
            p[nt] = s;
        }
        #pragma unroll
        for (int nt = 0; nt < 4; ++nt) {
            p[nt] += __shfl_xor(p[nt], 16, 64);
            p[nt] += __shfl_xor(p[nt], 32, 64);
        }
        if (lg == 0) {
            #pragma unroll
            for (int nt = 0; nt < 4; ++nt) pool[wid * 64 + 16 * nt + lr] = p[nt];
        }
    }
    __syncthreads();                                           // B7
    if (t < HDIM) {
        const float s = pool[t] + pool[64 + t] + pool[128 + t] + pool[192 + t];
        hbuf[((size_t)drug * B_PAIRS + b) * HDIM + t] = s * (1.0f / 64.0f);
    }
}

// ---------------------------------------------------------------------------
// Kernel 2: fused MLP. hidden = relu([h1|h2|fp1|fp2] @ Wm1 + bm1);
//           out = sigmoid(hidden . Wm2 + bm2).  M=4096, N=256, K=4224.
// Block: 32 pairs x full N=256 (4 waves x 64 cols). 33 K-steps of 128.
// K-window 128*s walks [h(128) | fp1(2048) | fp2(2048)] contiguously.
// ---------------------------------------------------------------------------
__global__ __launch_bounds__(256)
void fused_mlp_kernel(const float* __restrict__ fp1, const float* __restrict__ fp2,
                      const float* __restrict__ hbuf,
                      const unsigned short* __restrict__ Wm1t,  // [256][4224] bf16
                      const float* __restrict__ bm1, const float* __restrict__ Wm2,
                      const float* __restrict__ bm2, float* __restrict__ out) {
    __shared__ __align__(16) unsigned char lds[8192 + 512];
    float* pool = (float*)(lds + 8192);
    const int t = threadIdx.x;
    const int lane = t & 63, wid = t >> 6;
    const int lr = lane & 15, lg = lane >> 4;
    const int pair0 = blockIdx.x * 32;

    f32x4 acc[2][4];
    #pragma unroll
    for (int mf = 0; mf < 2; ++mf)
        #pragma unroll
        for (int nf = 0; nf < 4; ++nf) acc[mf][nf] = (f32x4){0.f, 0.f, 0.f, 0.f};

    const unsigned short* brow[4];
    #pragma unroll
    for (int nf = 0; nf < 4; ++nf)
        brow[nf] = Wm1t + (size_t)(64 * wid + 16 * nf + lr) * KTOT + 8 * lg;

    const int r  = t >> 3;           // staging row (pair) 0..31
    const int kc = (t & 7) << 4;     // staging k-chunk 0..112
    const int pr = pair0 + r;
    const unsigned sw = (unsigned)(r & 7) << 4;

    for (int s = 0; s < 33; ++s) {
        const int kglob = s << 7;
        // ---- load 16 fp32 for this thread's A slice ----
        float4 v0, v1, v2, v3;
        {
            const float* src;
            if (s == 0) {
                src = (kc < 64) ? (hbuf + (size_t)pr * HDIM + kc)
                                : (hbuf + (size_t)(B_PAIRS + pr) * HDIM + (kc - 64));
            } else if (s <= 16) {
                src = fp1 + (size_t)pr * FPDIM + (kglob - 128) + kc;
            } else {
                src = fp2 + (size_t)pr * FPDIM + (kglob - 2176) + kc;
            }
            const float4* s4 = (const float4*)src;
            v0 = s4[0]; v1 = s4[1]; v2 = s4[2]; v3 = s4[3];
        }
        __syncthreads();   // prev step's LDS reads done
        {
            uint4 w0 = make_uint4(pack2(v0.x, v0.y), pack2(v0.z, v0.w),
                                  pack2(v1.x, v1.y), pack2(v1.z, v1.w));
            uint4 w1 = make_uint4(pack2(v2.x, v2.y), pack2(v2.z, v2.w),
                                  pack2(v3.x, v3.y), pack2(v3.z, v3.w));
            *(uint4*)(lds + (unsigned)r * 256 + (((unsigned)(2 * kc))      ^ sw)) = w0;
            *(uint4*)(lds + (unsigned)r * 256 + (((unsigned)(2 * kc + 16)) ^ sw)) = w1;
        }
        __syncthreads();
        // ---- MFMA over this 128-k window ----
        const unsigned asw = (unsigned)(lr & 7) << 4;
        #pragma unroll
        for (int ks = 0; ks < 4; ++ks) {
            const unsigned kb = (unsigned)(64 * ks + 16 * lg);
            const bf16x8 a0 = *(const bf16x8*)(lds + (unsigned)lr * 256 + (kb ^ asw));
            const bf16x8 a1 = *(const bf16x8*)(lds + (unsigned)(16 + lr) * 256 + (kb ^ asw));
            #pragma unroll
            for (int nf = 0; nf < 4; ++nf) {
                const bf16x8 b = *(const bf16x8*)(brow[nf] + kglob + 32 * ks);
                acc[0][nf] = __builtin_amdgcn_mfma_f32_16x16x32_bf16(a0, b, acc[0][nf], 0, 0, 0);
                acc[1][nf] = __builtin_amdgcn_mfma_f32_16x16x32_bf16(a1, b, acc[1][nf], 0, 0, 0);
            }
        }
    }

    // ---- epilogue: bias, relu, dot Wm2, reduce, sigmoid ----
    float bm1v[4], wm2v[4];
    #pragma unroll
    for (int nf = 0; nf < 4; ++nf) {
        const int n = 64 * wid + 16 * nf + lr;
        bm1v[nf] = bm1[n];
        wm2v[nf] = Wm2[n];
    }
    #pragma unroll
    for (int mf = 0; mf < 2; ++mf) {
        #pragma unroll
        for (int reg = 0; reg < 4; ++reg) {
            float p = 0.f;
            #pragma unroll
            for (int nf = 0; nf < 4; ++nf)
                p += fmaxf(acc[mf][nf][reg] + bm1v[nf], 0.f) * wm2v[nf];
            p += __shfl_xor(p, 1, 64);
            p += __shfl_xor(p, 2, 64);
            p += __shfl_xor(p, 4, 64);
            p += __shfl_xor(p, 8, 64);
            if (lr == 0) pool[wid * 32 + 16 * mf + 4 * lg + reg] = p;
        }
    }
    __syncthreads();
    if (t < 32) {
        const float y = pool[t] + pool[32 + t] + pool[64 + t] + pool[96 + t] + bm2[0];
        out[pair0 + t] = 1.0f / (1.0f + expf(-y));
    }
}

extern "C" void kernel_launch(void* const* d_in, const int* in_sizes, int n_in,
                              void* d_out, int out_size, void* d_ws, size_t ws_size,
                              hipStream_t stream) {
    const float* x1  = (const float*)d_in[0];
    const float* x2  = (const float*)d_in[1];
    const int*   e1  = (const int*)d_in[2];
    const int*   e2  = (const int*)d_in[3];
    const float* fp1 = (const float*)d_in[4];
    const float* fp2 = (const float*)d_in[5];
    const float* W1  = (const float*)d_in[6];
    const float* b1  = (const float*)d_in[7];
    const float* W2  = (const float*)d_in[8];
    const float* b2  = (const float*)d_in[9];
    const float* Wm1 = (const float*)d_in[10];
    const float* bm1 = (const float*)d_in[11];
    const float* Wm2 = (const float*)d_in[12];
    const float* bm2 = (const float*)d_in[13];
    float* out  = (float*)d_out;

    float* hbuf = (float*)d_ws;                                          // 2 MB
    unsigned short* W1t  = (unsigned short*)((char*)d_ws + (2 << 20));   // 16 KB
    unsigned short* W2t  = W1t + HDIM * FDIM;                            // 8 KB
    unsigned short* Wm1t = (unsigned short*)((char*)d_ws + (3 << 20));   // 2.16 MB

    hipLaunchKernelGGL(prep_weights, dim3(16), dim3(256), 0, stream, W1, W2, W1t, W2t);
    hipLaunchKernelGGL(prep_wm1, dim3(132, 8), dim3(256), 0, stream, Wm1, Wm1t);
    hipLaunchKernelGGL(encode_kernel, dim3(2 * B_PAIRS), dim3(256), 0, stream,
                       x1, x2, e1, e2, W1t, b1, W2t, b2, hbuf);
    hipLaunchKernelGGL(fused_mlp_kernel, dim3(B_PAIRS / 32), dim3(256), 0, stream,
                       fp1, fp2, hbuf, Wm1t, bm1, Wm2, bm2, out);
}

// Round 5
// 210.916 us; speedup vs baseline: 7.2661x; 1.2786x over previous
//
#include <hip/hip_runtime.h>
#include <math.h>

#define B_PAIRS 4096
#define NNODES  64
#define NEDGES  256
#define FDIM    128
#define HDIM    64
#define FPDIM   2048
#define MDIM    256
#define KTOT    4224   // 2*HDIM + 2*FPDIM

typedef __attribute__((ext_vector_type(4))) float f32x4;
typedef __bf16 bf16x8 __attribute__((ext_vector_type(8)));

__device__ __forceinline__ unsigned short f2bf(float f) {
    union { float f; unsigned u; } v; v.f = f;
    unsigned r = v.u + 0x7FFF + ((v.u >> 16) & 1);   // RTNE
    return (unsigned short)(r >> 16);
}
__device__ __forceinline__ unsigned pack2(float a, float b) {
    return (unsigned)f2bf(a) | ((unsigned)f2bf(b) << 16);
}

// ---------------------------------------------------------------------------
// Kernel 0a: W1t[n][k]=W1[k][n], W2t[n][k]=W2[k][n] (bf16), grid-strided.
// ---------------------------------------------------------------------------
__global__ void prep_weights(const float* __restrict__ W1, const float* __restrict__ W2,
                             unsigned short* __restrict__ W1t, unsigned short* __restrict__ W2t) {
    const int t0 = blockIdx.x * 256 + threadIdx.x;
    const int stride = gridDim.x * 256;
    for (int i = t0; i < HDIM * FDIM; i += stride) {
        const int n = i >> 7, k = i & 127;
        W1t[i] = f2bf(W1[k * HDIM + n]);
    }
    for (int i = t0; i < HDIM * HDIM; i += stride) {
        const int n = i >> 6, k = i & 63;
        W2t[i] = f2bf(W2[k * HDIM + n]);
    }
}

// ---------------------------------------------------------------------------
// Kernel 0b: Wm1t[n][k] = bf16(Wm1[k][n]), n<256, k<4224. Tiled 32x32 via LDS.
// ---------------------------------------------------------------------------
__global__ __launch_bounds__(256)
void prep_wm1(const float* __restrict__ Wm1, unsigned short* __restrict__ Wm1t) {
    __shared__ float tile[32][33];
    const int k0 = blockIdx.x * 32, n0 = blockIdx.y * 32;
    const int t = threadIdx.x;
    const int c = t & 31, r8 = t >> 5;
    #pragma unroll
    for (int rr = r8; rr < 32; rr += 8)
        tile[rr][c] = Wm1[(size_t)(k0 + rr) * MDIM + n0 + c];
    __syncthreads();
    #pragma unroll
    for (int j = 0; j < 4; ++j) {
        const int n = n0 + r8 + 8 * j;
        Wm1t[(size_t)n * KTOT + k0 + c] = f2bf(tile[c][r8 + 8 * j]);
    }
}

// ---------------------------------------------------------------------------
// Kernel 1: per-graph GCN encoder, all-MFMA.
// LDS 36608 B -> 4 blocks/CU (was 44544 -> 3). u16-packed counts in u32[64][33]
// (padded stride 33 kills the 16-way bank conflicts of the old [64][64] int).
//   [    0,16384) Xb bf16[64][128] -> after step1: T2b[0,8K) + T3t[8K,16K)
//   [16384,24576) Ab bf16[64][64]
//   [24576,33024) cnt32 u32[64][33]; T1t bf16 8K overlaps [24576,32768)
//   [33024,36608) srcs/dsts/deg/pool
// ---------------------------------------------------------------------------
__global__ __launch_bounds__(256)
void encode_kernel(const float* __restrict__ x1, const float* __restrict__ x2,
                   const int* __restrict__ e1, const int* __restrict__ e2,
                   const unsigned short* __restrict__ W1t, const float* __restrict__ b1,
                   const unsigned short* __restrict__ W2t, const float* __restrict__ b2,
                   float* __restrict__ hbuf) {
    __shared__ __align__(16) unsigned char lds[36608];
    const int gid  = blockIdx.x;
    const int drug = gid >> 12;
    const int b    = gid & (B_PAIRS - 1);
    const float* x  = (drug ? x2 : x1) + (size_t)b * NNODES * FDIM;
    const int*   eg = (drug ? e2 : e1) + (size_t)b * 2 * NEDGES;

    const int t    = threadIdx.x;
    const int lane = t & 63, wid = t >> 6;
    const int lr   = lane & 15, lg = lane >> 4;
    const int mt   = wid;
    const int m0   = 16 * mt + 4 * lg;

    unsigned* cnt32 = (unsigned*)(lds + 24576);   // u32[64][33]
    int*   srcs = (int*)(lds + 33024);
    int*   dsts = (int*)(lds + 34048);
    int*   deg  = (int*)(lds + 35072);
    float* pool = (float*)(lds + 35328);

    // fire x loads early; overlap with edge/count phase
    float4 xv[8];
    const float4* xg = (const float4*)x;
    #pragma unroll
    for (int i = 0; i < 8; ++i) xv[i] = xg[t + 256 * i];

    // zero cnt32 (2112 u32 = 528 uint4)
    for (int i = t; i < 528; i += 256) ((uint4*)cnt32)[i] = make_uint4(0, 0, 0, 0);
    { srcs[t] = eg[t]; dsts[t] = eg[NEDGES + t]; }
    if (t < NNODES) deg[t] = 0;
    __syncthreads();                                           // B0
    {
        const int d = dsts[t], s = srcs[t];
        atomicAdd(&deg[d], 1);
        atomicAdd(&cnt32[d * 33 + (s >> 1)], 1u << ((s & 1) * 16));
    }
    __syncthreads();                                           // B1

    // build A-hat bf16 swizzled: Ab[r][c] = (cnt + (r==c)) * rsqrt(deg_r+1) * rsqrt(deg_c+1)
    {
        const int r = t >> 2, c0 = (t & 3) << 4;
        const float dr = rsqrtf((float)deg[r] + 1.0f);
        unsigned char* arow = lds + 16384 + r * 128;
        const unsigned sw = (r & 7) << 4;
        #pragma unroll
        for (int j = 0; j < 16; j += 2) {
            const int c = c0 + j;                    // even
            const unsigned w = cnt32[r * 33 + (c >> 1)];
            const float n0 = (float)((w & 0xffffu) + (r == c     ? 1u : 0u));
            const float n1 = (float)((w >> 16)     + (r == c + 1 ? 1u : 0u));
            const float v0 = n0 * dr * rsqrtf((float)deg[c]     + 1.0f);
            const float v1 = n1 * dr * rsqrtf((float)deg[c + 1] + 1.0f);
            *(unsigned*)(arow + (((unsigned)(2 * c)) ^ sw)) = pack2(v0, v1);
        }
    }
    // stage Xb bf16 swizzled
    #pragma unroll
    for (int i = 0; i < 8; ++i) {
        const int f = t + 256 * i, r = f >> 5, c = (f & 31) << 2;
        const unsigned lo = pack2(xv[i].x, xv[i].y);
        const unsigned hi = pack2(xv[i].z, xv[i].w);
        const unsigned off = (unsigned)r * 256 + (((unsigned)(2 * c)) ^ ((unsigned)(r & 7) << 4));
        *(unsigned long long*)(lds + off) = (unsigned long long)lo | ((unsigned long long)hi << 32);
    }
    __syncthreads();                                           // B2 (cnt32 dead after this)

    // step1: T1 = Xb @ W1 -> T1t[featH][node] (overwrites cnt32 region)
    {
        f32x4 acc[4];
        #pragma unroll
        for (int nt = 0; nt < 4; ++nt) acc[nt] = (f32x4){0.f, 0.f, 0.f, 0.f};
        const int ar = 16 * mt + lr;
        const unsigned asw = (unsigned)(ar & 7) << 4;
        #pragma unroll
        for (int ks = 0; ks < 4; ++ks) {
            const unsigned kb = 64 * ks + 16 * lg;
            const bf16x8 a = *(const bf16x8*)(lds + (unsigned)ar * 256 + (kb ^ asw));
            #pragma unroll
            for (int nt = 0; nt < 4; ++nt) {
                const bf16x8 bw = *(const bf16x8*)(W1t + (16 * nt + lr) * 128 + 32 * ks + 8 * lg);
                acc[nt] = __builtin_amdgcn_mfma_f32_16x16x32_bf16(a, bw, acc[nt], 0, 0, 0);
            }
        }
        #pragma unroll
        for (int nt = 0; nt < 4; ++nt) {
            const int f = 16 * nt + lr;
            const unsigned lo = pack2(acc[nt][0], acc[nt][1]);
            const unsigned hi = pack2(acc[nt][2], acc[nt][3]);
            const unsigned off = 24576u + (unsigned)f * 128 + (((unsigned)(2 * m0)) ^ ((unsigned)(f & 7) << 4));
            *(unsigned long long*)(lds + off) = (unsigned long long)lo | ((unsigned long long)hi << 32);
        }
    }
    __syncthreads();                                           // B3

    // step2: T2^T = T1t @ A^T (+b1, relu) -> T2b[node][featH]
    {
        f32x4 acc[4];
        #pragma unroll
        for (int nt = 0; nt < 4; ++nt) acc[nt] = (f32x4){0.f, 0.f, 0.f, 0.f};
        const int ar = 16 * mt + lr;
        const unsigned asw = (unsigned)(ar & 7) << 4;
        #pragma unroll
        for (int ks = 0; ks < 2; ++ks) {
            const unsigned kb = 64 * ks + 16 * lg;
            const bf16x8 a = *(const bf16x8*)(lds + 24576u + (unsigned)ar * 128 + (kb ^ asw));
            #pragma unroll
            for (int nt = 0; nt < 4; ++nt) {
                const int d = 16 * nt + lr;
                const bf16x8 bw = *(const bf16x8*)(lds + 16384u + (unsigned)d * 128 + (kb ^ ((unsigned)(d & 7) << 4)));
                acc[nt] = __builtin_amdgcn_mfma_f32_16x16x32_bf16(a, bw, acc[nt], 0, 0, 0);
            }
        }
        const float4 b1v = *(const float4*)(b1 + m0);
        #pragma unroll
        for (int nt = 0; nt < 4; ++nt) {
            const int d = 16 * nt + lr;
            const float v0 = fmaxf(acc[nt][0] + b1v.x, 0.f);
            const float v1 = fmaxf(acc[nt][1] + b1v.y, 0.f);
            const float v2 = fmaxf(acc[nt][2] + b1v.z, 0.f);
            const float v3 = fmaxf(acc[nt][3] + b1v.w, 0.f);
            const unsigned off = (unsigned)d * 128 + (((unsigned)(2 * m0)) ^ ((unsigned)(d & 7) << 4));
            *(unsigned long long*)(lds + off) =
                (unsigned long long)pack2(v0, v1) | ((unsigned long long)pack2(v2, v3) << 32);
        }
    }
    __syncthreads();                                           // B4

    // step3: T3 = T2b @ W2 -> T3t[outH][node]
    {
        f32x4 acc[4];
        #pragma unroll
        for (int nt = 0; nt < 4; ++nt) acc[nt] = (f32x4){0.f, 0.f, 0.f, 0.f};
        const int ar = 16 * mt + lr;
        const unsigned asw = (unsigned)(ar & 7) << 4;
        #pragma unroll
        for (int ks = 0; ks < 2; ++ks) {
            const unsigned kb = 64 * ks + 16 * lg;
            const bf16x8 a = *(const bf16x8*)(lds + (unsigned)ar * 128 + (kb ^ asw));
            #pragma unroll
            for (int nt = 0; nt < 4; ++nt) {
                const bf16x8 bw = *(const bf16x8*)(W2t + (16 * nt + lr) * 64 + 32 * ks + 8 * lg);
                acc[nt] = __builtin_amdgcn_mfma_f32_16x16x32_bf16(a, bw, acc[nt], 0, 0, 0);
            }
        }
        #pragma unroll
        for (int nt = 0; nt < 4; ++nt) {
            const int n = 16 * nt + lr;
            const unsigned lo = pack2(acc[nt][0], acc[nt][1]);
            const unsigned hi = pack2(acc[nt][2], acc[nt][3]);
            const unsigned off = 8192u + (unsigned)n * 128 + (((unsigned)(2 * m0)) ^ ((unsigned)(n & 7) << 4));
            *(unsigned long long*)(lds + off) = (unsigned long long)lo | ((unsigned long long)hi << 32);
        }
    }
    __syncthreads();                                           // B5

    // step4: h2 = Ab @ T3 (+b2, relu) -> pool
    {
        f32x4 acc[4];
        #pragma unroll
        for (int nt = 0; nt < 4; ++nt) acc[nt] = (f32x4){0.f, 0.f, 0.f, 0.f};
        const int ar = 16 * mt + lr;
        const unsigned asw = (unsigned)(ar & 7) << 4;
        #pragma unroll
        for (int ks = 0; ks < 2; ++ks) {
            const unsigned kb = 64 * ks + 16 * lg;
            const bf16x8 a = *(const bf16x8*)(lds + 16384u + (unsigned)ar * 128 + (kb ^ asw));
            #pragma unroll
            for (int nt = 0; nt < 4; ++nt) {
                const int n = 16 * nt + lr;
                const bf16x8 bw = *(const bf16x8*)(lds + 8192u + (unsigned)n * 128 + (kb ^ ((unsigned)(n & 7) << 4)));
                acc[nt] = __builtin_amdgcn_mfma_f32_16x16x32_bf16(a, bw, acc[nt], 0, 0, 0);
            }
        }
        float p[4];
        #pragma unroll
        for (int nt = 0; nt < 4; ++nt) {
            const float bb = b2[16 * nt + lr];
            float s = 0.f;
            #pragma unroll
            for (int r = 0; r < 4; ++r) s += fmaxf(acc[nt][r] + bb, 0.f);
            p[nt] = s;
        }
        #pragma unroll
        for (int nt = 0; nt < 4; ++nt) {
            p[nt] += __shfl_xor(p[nt], 16, 64);
            p[nt] += __shfl_xor(p[nt], 32, 64);
        }
        if (lg == 0) {
            #pragma unroll
            for (int nt = 0; nt < 4; ++nt) pool[wid * 64 + 16 * nt + lr] = p[nt];
        }
    }
    __syncthreads();                                           // B6
    if (t < HDIM) {
        const float s = pool[t] + pool[64 + t] + pool[128 + t] + pool[192 + t];
        hbuf[((size_t)drug * B_PAIRS + b) * HDIM + t] = s * (1.0f / 64.0f);
    }
}

// ---------------------------------------------------------------------------
// Kernel 2: fused MLP. hidden = relu([h1|h2|fp1|fp2] @ Wm1 + bm1);
//           out = sigmoid(hidden . Wm2 + bm2).  M=4096, N=256, K=4224.
// 16 pairs/block -> 256 blocks (full GPU). Double-buffered A tile (2x4KB),
// next-step loads issued before the single barrier, written after MFMAs.
// ---------------------------------------------------------------------------
__global__ __launch_bounds__(256)
void fused_mlp_kernel(const float* __restrict__ fp1, const float* __restrict__ fp2,
                      const float* __restrict__ hbuf,
                      const unsigned short* __restrict__ Wm1t,  // [256][4224] bf16
                      const float* __restrict__ bm1, const float* __restrict__ Wm2,
                      const float* __restrict__ bm2, float* __restrict__ out) {
    __shared__ __align__(16) unsigned char lds[8448];
    float* pool = (float*)(lds + 8192);            // 64 floats
    const int t = threadIdx.x;
    const int lane = t & 63, wid = t >> 6;
    const int lr = lane & 15, lg = lane >> 4;
    const int pair0 = blockIdx.x * 16;

    const int r  = t >> 4;                         // staging pair row 0..15
    const int kc = (t & 15) << 3;                  // staging k-offset 0..120
    const int pr = pair0 + r;
    const unsigned wOff = (unsigned)r * 256 + (((unsigned)(2 * kc)) ^ ((unsigned)(r & 7) << 4));

    f32x4 acc[4];
    #pragma unroll
    for (int nf = 0; nf < 4; ++nf) acc[nf] = (f32x4){0.f, 0.f, 0.f, 0.f};

    const unsigned short* brow[4];
    #pragma unroll
    for (int nf = 0; nf < 4; ++nf)
        brow[nf] = Wm1t + (size_t)(64 * wid + 16 * nf + lr) * KTOT + 8 * lg;

    float4 va, vb;
    #define LOAD_A(s)                                                                  \
        {                                                                              \
            const float* src;                                                          \
            if ((s) == 0)                                                              \
                src = (kc < 64) ? hbuf + (size_t)pr * HDIM + kc                        \
                                : hbuf + (size_t)(B_PAIRS + pr) * HDIM + (kc - 64);    \
            else if ((s) <= 16)                                                        \
                src = fp1 + (size_t)pr * FPDIM + ((s) - 1) * 128 + kc;                 \
            else                                                                       \
                src = fp2 + (size_t)pr * FPDIM + ((s) - 17) * 128 + kc;                \
            va = ((const float4*)src)[0];                                              \
            vb = ((const float4*)src)[1];                                              \
        }
    #define STORE_A(base)                                                              \
        *(uint4*)((base) + wOff) = make_uint4(pack2(va.x, va.y), pack2(va.z, va.w),    \
                                              pack2(vb.x, vb.y), pack2(vb.z, vb.w));

    LOAD_A(0);
    STORE_A(lds);
    for (int s = 0; s < 33; ++s) {
        const bool more = (s + 1 < 33);
        if (more) LOAD_A(s + 1);                   // issue next-step globals early
        __syncthreads();                           // buf[s&1] ready; prev reads drained
        const unsigned char* buf = lds + (unsigned)((s & 1) << 12);
        const unsigned asw = (unsigned)(lr & 7) << 4;
        const int kglob = s << 7;
        #pragma unroll
        for (int ks = 0; ks < 4; ++ks) {
            const unsigned kb = (unsigned)(64 * ks + 16 * lg);
            const bf16x8 a = *(const bf16x8*)(buf + (unsigned)lr * 256 + (kb ^ asw));
            #pragma unroll
            for (int nf = 0; nf < 4; ++nf) {
                const bf16x8 bw = *(const bf16x8*)(brow[nf] + kglob + 32 * ks);
                acc[nf] = __builtin_amdgcn_mfma_f32_16x16x32_bf16(a, bw, acc[nf], 0, 0, 0);
            }
        }
        if (more) STORE_A(lds + (unsigned)(((s + 1) & 1) << 12));
    }

    // epilogue: bias, relu, dot Wm2, reduce over n, sigmoid
    float bm1v[4], wm2v[4];
    #pragma unroll
    for (int nf = 0; nf < 4; ++nf) {
        const int n = 64 * wid + 16 * nf + lr;
        bm1v[nf] = bm1[n];
        wm2v[nf] = Wm2[n];
    }
    #pragma unroll
    for (int reg = 0; reg < 4; ++reg) {            // row m = 4*lg + reg
        float p = 0.f;
        #pragma unroll
        for (int nf = 0; nf < 4; ++nf)
            p += fmaxf(acc[nf][reg] + bm1v[nf], 0.f) * wm2v[nf];
        p += __shfl_xor(p, 1, 64);
        p += __shfl_xor(p, 2, 64);
        p += __shfl_xor(p, 4, 64);
        p += __shfl_xor(p, 8, 64);
        if (lr == 0) pool[wid * 16 + 4 * lg + reg] = p;
    }
    __syncthreads();
    if (t < 16) {
        const float y = pool[t] + pool[16 + t] + pool[32 + t] + pool[48 + t] + bm2[0];
        out[pair0 + t] = 1.0f / (1.0f + expf(-y));
    }
    #undef LOAD_A
    #undef STORE_A
}

extern "C" void kernel_launch(void* const* d_in, const int* in_sizes, int n_in,
                              void* d_out, int out_size, void* d_ws, size_t ws_size,
                              hipStream_t stream) {
    const float* x1  = (const float*)d_in[0];
    const float* x2  = (const float*)d_in[1];
    const int*   e1  = (const int*)d_in[2];
    const int*   e2  = (const int*)d_in[3];
    const float* fp1 = (const float*)d_in[4];
    const float* fp2 = (const float*)d_in[5];
    const float* W1  = (const float*)d_in[6];
    const float* b1  = (const float*)d_in[7];
    const float* W2  = (const float*)d_in[8];
    const float* b2  = (const float*)d_in[9];
    const float* Wm1 = (const float*)d_in[10];
    const float* bm1 = (const float*)d_in[11];
    const float* Wm2 = (const float*)d_in[12];
    const float* bm2 = (const float*)d_in[13];
    float* out  = (float*)d_out;

    float* hbuf = (float*)d_ws;                                          // 2 MB
    unsigned short* W1t  = (unsigned short*)((char*)d_ws + (2 << 20));   // 16 KB
    unsigned short* W2t  = W1t + HDIM * FDIM;                            // 8 KB
    unsigned short* Wm1t = (unsigned short*)((char*)d_ws + (3 << 20));   // 2.16 MB

    hipLaunchKernelGGL(prep_weights, dim3(16), dim3(256), 0, stream, W1, W2, W1t, W2t);
    hipLaunchKernelGGL(prep_wm1, dim3(132, 8), dim3(256), 0, stream, Wm1, Wm1t);
    hipLaunchKernelGGL(encode_kernel, dim3(2 * B_PAIRS), dim3(256), 0, stream,
                       x1, x2, e1, e2, W1t, b1, W2t, b2, hbuf);
    hipLaunchKernelGGL(fused_mlp_kernel, dim3(B_PAIRS / 16), dim3(256), 0, stream,
                       fp1, fp2, hbuf, Wm1t, bm1, Wm2, bm2, out);
}